// Round 5
// baseline (155.346 us; speedup 1.0000x reference)
//
#include <hip/hip_runtime.h>
#include <math.h>

#define M_ROWS 4096
#define IN_DIM 64
#define NCLS 10
#define ROW_STRIDE 74   // 64 tau + 10 labels
#define TWO_PI_F 6.283185307179586f
#define NPAIR 2080      // 64*65/2 upper-triangular tile pairs
#define NBLK_MLP 512    // 8 rows per block, 8 roles per row

// ---------------- phi (Bessel-I0-based) ----------------
__device__ __forceinline__ float phi_f_eval(float s) {
    float t = s * (1.0f / 7.5f);
    float t2 = t * t;
    float p = 0.0045813f;
    p = fmaf(p, t2, 0.0360768f);
    p = fmaf(p, t2, 0.2659732f);
    p = fmaf(p, t2, 1.2067492f);
    p = fmaf(p, t2, 3.0899424f);
    p = fmaf(p, t2, 3.5156229f);
    p = fmaf(p, t2, 1.0f);
    return __expf(-0.5f * s) * p;
}

__device__ __forceinline__ float phi_g_eval(float s) {
    float r = __builtin_amdgcn_rcpf(s);
    float u = 7.5f * r;
    float p = 0.00392377f;
    p = fmaf(p, u, -0.01647633f);
    p = fmaf(p, u, 0.02635537f);
    p = fmaf(p, u, -0.02057706f);
    p = fmaf(p, u, 0.0091628f);
    p = fmaf(p, u, -0.00157565f);
    p = fmaf(p, u, 0.00225319f);
    p = fmaf(p, u, 0.01328592f);
    p = fmaf(p, u, 0.39894228f);
    return __builtin_amdgcn_sqrtf(2.0f * r) * p;
}

#define PHI_F_75 0.21445709f   // phi_f(7.5)

__device__ __forceinline__ float phi_eval(float s) {
    float f = phi_f_eval(fminf(s, 7.5f));
    float g = phi_g_eval(fmaxf(s, 7.5f));
    return f - PHI_F_75 + g;
}

__device__ __forceinline__ float fast_tanh(float x) {
    float e = __expf(2.0f * x);
    float r = __builtin_amdgcn_rcpf(e + 1.0f);
    return fmaf(-2.0f, r, 1.0f);
}

__device__ __forceinline__ float waveReduce(float v) {
    v += __shfl_down(v, 32, 64);
    v += __shfl_down(v, 16, 64);
    v += __shfl_down(v, 8, 64);
    v += __shfl_down(v, 4, 64);
    v += __shfl_down(v, 2, 64);
    v += __shfl_down(v, 1, 64);
    return v;
}

__device__ __forceinline__ double waveReduceD(double v) {
    v += __shfl_down(v, 32, 64);
    v += __shfl_down(v, 16, 64);
    v += __shfl_down(v, 8, 64);
    v += __shfl_down(v, 4, 64);
    v += __shfl_down(v, 2, 64);
    v += __shfl_down(v, 1, 64);
    return v;
}

// register-select without dynamic indexing
__device__ __forceinline__ float sel4(float v0, float v1, float v2, float v3, int r) {
    float a = (r & 1) ? v1 : v0;
    float b = (r & 1) ? v3 : v2;
    return (r & 2) ? b : a;
}
__device__ __forceinline__ float sel8(float v0, float v1, float v2, float v3,
                                      float v4, float v5, float v6, float v7, int r) {
    float a = sel4(v0, v1, v2, v3, r);
    float b = sel4(v4, v5, v6, v7, r);
    return (r & 4) ? b : a;
}

// -------- LDS layout (floats), rows padded so 8 roles hit disjoint bank quads
#define P_W1   0        // 64 rows x stride 36
#define P_W2   2304     // 32 rows x stride 20
#define P_WD2  2944     // 16 rows x stride 36
#define P_WD3  3520     // 32 rows x stride 68
#define P_W3   5696     // 16x2
#define P_WD1  5728     // 2x16
#define P_B1   5760
#define P_B2   5792
#define P_B3   5808
#define P_BD1  5810
#define P_BD2  5826
#define P_BD3  5858
#define P_MU   5922
#define P_VAR  5942
#define P_PRB  5952
#define SMT    5962

// Kernel 1: MLP, 8 roles per row (row = tid&7, role = tid>>3), 512 blocks ->
// 2 waves/CU. Role r owns indices ≡ r (mod 8); butterfly shfl_xor(8/16/32)
// completes each dot-product in all lanes.
__global__ __launch_bounds__(64, 1) void k_mlp(
    const float* __restrict__ batch,
    const float* __restrict__ We1, const float* __restrict__ be1,
    const float* __restrict__ We2, const float* __restrict__ be2,
    const float* __restrict__ We3, const float* __restrict__ be3,
    const float* __restrict__ Wd1, const float* __restrict__ bd1,
    const float* __restrict__ Wd2, const float* __restrict__ bd2,
    const float* __restrict__ Wd3, const float* __restrict__ bd3,
    const float* __restrict__ means, const float* __restrict__ vars,
    const float* __restrict__ probs,
    float2* __restrict__ zbuf,
    float* __restrict__ recp, float* __restrict__ Bp,
    float* __restrict__ clsp, float* __restrict__ labp,
    int* __restrict__ cnt,
    float gamma)
{
    __shared__ __align__(16) float sm[SMT];
    const int tid = threadIdx.x;

    if (blockIdx.x == 0 && tid == 0) *cnt = 0;   // reset k_pair's done-counter

    for (int idx = tid; idx < 2048; idx += 64) { int i = idx >> 5, j = idx & 31; sm[P_W1  + i * 36 + j] = We1[idx]; }
    for (int idx = tid; idx < 512;  idx += 64) { int i = idx >> 4, j = idx & 15; sm[P_W2  + i * 20 + j] = We2[idx]; }
    for (int idx = tid; idx < 512;  idx += 64) { int i = idx >> 5, j = idx & 31; sm[P_WD2 + i * 36 + j] = Wd2[idx]; }
    for (int idx = tid; idx < 2048; idx += 64) { int i = idx >> 6, j = idx & 63; sm[P_WD3 + i * 68 + j] = Wd3[idx]; }
    if (tid < 32) sm[P_W3 + tid] = We3[tid];
    else          sm[P_WD1 + tid - 32] = Wd1[tid - 32];
    if (tid < 32) sm[P_B1 + tid] = be1[tid];
    if (tid < 16) sm[P_B2 + tid] = be2[tid];
    if (tid < 2)  sm[P_B3 + tid] = be3[tid];
    if (tid < 16) sm[P_BD1 + tid] = bd1[tid];
    if (tid < 32) sm[P_BD2 + tid] = bd2[tid];
    sm[P_BD3 + tid] = bd3[tid];
    if (tid < 20) sm[P_MU + tid] = means[tid];
    if (tid < 10) sm[P_VAR + tid] = vars[tid];
    if (tid < 10) sm[P_PRB + tid] = probs[tid];
    __syncthreads();

    const int rw = tid & 7;          // row within block
    const int r  = tid >> 3;         // role 0..7
    const int row = blockIdx.x * 8 + rw;
    const float* rp = batch + (size_t)row * ROW_STRIDE;

    // tau elements this role owns: indices r + 8k
    float taus[8];
#pragma unroll
    for (int k = 0; k < 8; k++) taus[k] = rp[r + 8 * k];

    // ---- encoder L1: 64 -> 32 ----
    float a1[32];
#pragma unroll
    for (int j = 0; j < 32; j++) a1[j] = 0.0f;
#pragma unroll
    for (int k = 0; k < 8; k++) {
        const int i = r + 8 * k;
        const float4* wr = (const float4*)&sm[P_W1 + i * 36];
        const float ti = taus[k];
#pragma unroll
        for (int jj = 0; jj < 8; jj++) {
            float4 w = wr[jj];
            a1[4 * jj + 0] = fmaf(ti, w.x, a1[4 * jj + 0]);
            a1[4 * jj + 1] = fmaf(ti, w.y, a1[4 * jj + 1]);
            a1[4 * jj + 2] = fmaf(ti, w.z, a1[4 * jj + 2]);
            a1[4 * jj + 3] = fmaf(ti, w.w, a1[4 * jj + 3]);
        }
    }
#pragma unroll
    for (int j = 0; j < 32; j++) {
        a1[j] += __shfl_xor(a1[j], 8, 64);
        a1[j] += __shfl_xor(a1[j], 16, 64);
        a1[j] += __shfl_xor(a1[j], 32, 64);
    }
    float x1own[4];
#pragma unroll
    for (int k = 0; k < 4; k++)
        x1own[k] = fast_tanh(sel8(a1[8 * k], a1[8 * k + 1], a1[8 * k + 2], a1[8 * k + 3],
                                  a1[8 * k + 4], a1[8 * k + 5], a1[8 * k + 6], a1[8 * k + 7], r)
                             + sm[P_B1 + r + 8 * k]);

    // ---- encoder L2: 32 -> 16 ----
    float a2[16];
#pragma unroll
    for (int j = 0; j < 16; j++) a2[j] = 0.0f;
#pragma unroll
    for (int k = 0; k < 4; k++) {
        const int i = r + 8 * k;
        const float4* wr = (const float4*)&sm[P_W2 + i * 20];
        const float x = x1own[k];
#pragma unroll
        for (int jj = 0; jj < 4; jj++) {
            float4 w = wr[jj];
            a2[4 * jj + 0] = fmaf(x, w.x, a2[4 * jj + 0]);
            a2[4 * jj + 1] = fmaf(x, w.y, a2[4 * jj + 1]);
            a2[4 * jj + 2] = fmaf(x, w.z, a2[4 * jj + 2]);
            a2[4 * jj + 3] = fmaf(x, w.w, a2[4 * jj + 3]);
        }
    }
#pragma unroll
    for (int j = 0; j < 16; j++) {
        a2[j] += __shfl_xor(a2[j], 8, 64);
        a2[j] += __shfl_xor(a2[j], 16, 64);
        a2[j] += __shfl_xor(a2[j], 32, 64);
    }
    float x2own[2];
#pragma unroll
    for (int k = 0; k < 2; k++)
        x2own[k] = fast_tanh(sel8(a2[8 * k], a2[8 * k + 1], a2[8 * k + 2], a2[8 * k + 3],
                                  a2[8 * k + 4], a2[8 * k + 5], a2[8 * k + 6], a2[8 * k + 7], r)
                             + sm[P_B2 + r + 8 * k]);

    // ---- encoder L3: 16 -> 2 (z) ----
    float z0 = 0.0f, z1 = 0.0f;
#pragma unroll
    for (int k = 0; k < 2; k++) {
        const int i = r + 8 * k;
        z0 = fmaf(x2own[k], sm[P_W3 + 2 * i], z0);
        z1 = fmaf(x2own[k], sm[P_W3 + 2 * i + 1], z1);
    }
    z0 += __shfl_xor(z0, 8, 64); z0 += __shfl_xor(z0, 16, 64); z0 += __shfl_xor(z0, 32, 64);
    z1 += __shfl_xor(z1, 8, 64); z1 += __shfl_xor(z1, 16, 64); z1 += __shfl_xor(z1, 32, 64);
    z0 += sm[P_B3 + 0];
    z1 += sm[P_B3 + 1];
    if (r == 0) zbuf[row] = make_float2(z0, z1);

    // ---- decoder d1: 2 -> 16 ----
    float h1own[2];
#pragma unroll
    for (int k = 0; k < 2; k++) {
        const int j = r + 8 * k;
        float acc = sm[P_BD1 + j];
        acc = fmaf(z0, sm[P_WD1 + j], acc);
        acc = fmaf(z1, sm[P_WD1 + 16 + j], acc);
        h1own[k] = fast_tanh(acc);
    }

    // ---- decoder d2: 16 -> 32 ----
    float a3[32];
#pragma unroll
    for (int j = 0; j < 32; j++) a3[j] = 0.0f;
#pragma unroll
    for (int k = 0; k < 2; k++) {
        const int i = r + 8 * k;
        const float4* wr = (const float4*)&sm[P_WD2 + i * 36];
        const float x = h1own[k];
#pragma unroll
        for (int jj = 0; jj < 8; jj++) {
            float4 w = wr[jj];
            a3[4 * jj + 0] = fmaf(x, w.x, a3[4 * jj + 0]);
            a3[4 * jj + 1] = fmaf(x, w.y, a3[4 * jj + 1]);
            a3[4 * jj + 2] = fmaf(x, w.z, a3[4 * jj + 2]);
            a3[4 * jj + 3] = fmaf(x, w.w, a3[4 * jj + 3]);
        }
    }
#pragma unroll
    for (int j = 0; j < 32; j++) {
        a3[j] += __shfl_xor(a3[j], 8, 64);
        a3[j] += __shfl_xor(a3[j], 16, 64);
        a3[j] += __shfl_xor(a3[j], 32, 64);
    }
    float h2own[4];
#pragma unroll
    for (int k = 0; k < 4; k++)
        h2own[k] = fast_tanh(sel8(a3[8 * k], a3[8 * k + 1], a3[8 * k + 2], a3[8 * k + 3],
                                  a3[8 * k + 4], a3[8 * k + 5], a3[8 * k + 6], a3[8 * k + 7], r)
                             + sm[P_BD2 + r + 8 * k]);

    // ---- decoder d3: 32 -> 64 + rec ----
    float a4[64];
#pragma unroll
    for (int j = 0; j < 64; j++) a4[j] = 0.0f;
#pragma unroll
    for (int k = 0; k < 4; k++) {
        const int i = r + 8 * k;
        const float4* wr = (const float4*)&sm[P_WD3 + i * 68];
        const float x = h2own[k];
#pragma unroll
        for (int jj = 0; jj < 16; jj++) {
            float4 w = wr[jj];
            a4[4 * jj + 0] = fmaf(x, w.x, a4[4 * jj + 0]);
            a4[4 * jj + 1] = fmaf(x, w.y, a4[4 * jj + 1]);
            a4[4 * jj + 2] = fmaf(x, w.z, a4[4 * jj + 2]);
            a4[4 * jj + 3] = fmaf(x, w.w, a4[4 * jj + 3]);
        }
    }
#pragma unroll
    for (int j = 0; j < 64; j++) {
        a4[j] += __shfl_xor(a4[j], 8, 64);
        a4[j] += __shfl_xor(a4[j], 16, 64);
        a4[j] += __shfl_xor(a4[j], 32, 64);
    }
    float rec = 0.0f;
#pragma unroll
    for (int k = 0; k < 8; k++) {
        float dec = sel8(a4[8 * k], a4[8 * k + 1], a4[8 * k + 2], a4[8 * k + 3],
                         a4[8 * k + 4], a4[8 * k + 5], a4[8 * k + 6], a4[8 * k + 7], r)
                    + sm[P_BD3 + r + 8 * k];
        float e = dec - taus[k];
        rec = fmaf(e, e, rec);
    }

    // ---- B term + class CE: only role 0 (one lane per row) ----
    float Bacc = 0.0f, cls = 0.0f, suml = 0.0f;
    if (r == 0) {
        const float two_g = 2.0f * gamma;
        const float inv_m = 1.0f / (float)M_ROWS;
        float lg[NCLS];
        float mx = -3.0e38f;
#pragma unroll
        for (int c = 0; c < NCLS; c++) {
            float d0 = z0 - sm[P_MU + 2 * c];
            float d1 = z1 - sm[P_MU + 2 * c + 1];
            float sqc = fmaf(d0, d0, d1 * d1);
            float vc = sm[P_VAR + c];
            float lgc = __logf(sm[P_PRB + c]) - __logf(TWO_PI_F * vc)
                        - sqc * 0.5f * __builtin_amdgcn_rcpf(vc);
            lg[c] = lgc;
            mx = fmaxf(mx, lgc);

            float den = vc + two_g;
            float sB = sqc * 0.5f * __builtin_amdgcn_rcpf(den);
            float coef = 2.0f * inv_m * sm[P_PRB + c] * __builtin_amdgcn_rsqf(TWO_PI_F * den);
            Bacc = fmaf(coef, phi_eval(sB), Bacc);
        }
        float esum = 0.0f;
#pragma unroll
        for (int c = 0; c < NCLS; c++) esum += __expf(lg[c] - mx);
        float lse = __logf(esum) + mx;

        float ce = 0.0f;
#pragma unroll
        for (int c = 0; c < NCLS; c++) {
            float lb = rp[IN_DIM + c];
            suml += lb;
            ce = fmaf(lb, lse - lg[c], ce);
        }
        cls = (suml == 1.0f) ? ce : 0.0f;
    }

    float r0 = waveReduce(rec);
    float r1 = waveReduce(Bacc);
    float r2 = waveReduce(cls);
    float r3 = waveReduce(suml);
    if (tid == 0) {
        recp[blockIdx.x] = r0;
        Bp[blockIdx.x]   = r1;
        clsp[blockIdx.x] = r2;
        labp[blockIdx.x] = r3;
    }
}

// Kernel 2: pairwise A term + fused finalize in the last-done block.
// Triangular grid; diagonal tiles counted once, off-diagonal weighted x2.
__global__ __launch_bounds__(64, 4) void k_pair(
    const float2* __restrict__ z, float* __restrict__ Apart,
    const float* __restrict__ recp, const float* __restrict__ Bp,
    const float* __restrict__ clsp, const float* __restrict__ labp,
    const float* __restrict__ means, const float* __restrict__ vars,
    const float* __restrict__ probs,
    float* __restrict__ out, int* __restrict__ cnt,
    float inv4g, float gamma)
{
    const int p = blockIdx.x;
    int tj = (int)((__builtin_amdgcn_sqrtf(8.0f * (float)p + 1.0f) - 1.0f) * 0.5f);
    while ((tj + 1) * (tj + 2) / 2 <= p) tj++;
    while (tj * (tj + 1) / 2 > p) tj--;
    const int ti = p - tj * (tj + 1) / 2;

    const int lane = threadIdx.x;
    __shared__ float2 zjs[64];
    float2 zi = z[ti * 64 + lane];
    zjs[lane] = z[tj * 64 + lane];
    __syncthreads();

    float acc0 = 0.0f, acc1 = 0.0f;
#pragma unroll 8
    for (int jj = 0; jj < 64; jj += 2) {
        float2 a = zjs[jj], b = zjs[jj + 1];
        float dx0 = zi.x - a.x, dy0 = zi.y - a.y;
        float dx1 = zi.x - b.x, dy1 = zi.y - b.y;
        acc0 += phi_eval(fmaf(dx0, dx0, dy0 * dy0) * inv4g);
        acc1 += phi_eval(fmaf(dx1, dx1, dy1 * dy1) * inv4g);
    }
    float tot = waveReduce(acc0 + acc1);

    int old = 0;
    if (lane == 0) {
        Apart[p] = (ti == tj) ? tot : 2.0f * tot;
        __threadfence();                 // make Apart[p] visible before count
        old = atomicAdd(cnt, 1);
    }
    old = __shfl(old, 0, 64);
    if (old != NPAIR - 1) return;

    // ---- last block: finalize ----
    __threadfence();   // acquire: all other blocks' Apart stores are visible

    const double m = (double)M_ROWS;
    const double gam = (double)gamma;
    const double invA = 1.0 / (m * m * sqrt(2.0 * M_PI * 2.0 * gam));

    double av = 0.0;
#pragma unroll
    for (int k = 0; k < 33; k++) {
        int idx = lane + 64 * k;
        if (idx < NPAIR) av += (double)Apart[idx];
    }

    double cv = 0.0;
    for (int t = lane; t < 100; t += 64) {
        int ci = t / 10, cj = t - 10 * (t / 10);
        float vm = vars[ci] + vars[cj];
        float d0 = means[2 * ci] - means[2 * cj];
        float d1 = means[2 * ci + 1] - means[2 * cj + 1];
        float c1 = fmaf(d0, d0, d1 * d1);
        float s = c1 / (2.0f * vm + 4.0f * gamma);
        float c2 = phi_eval(s);
        float c3 = probs[ci] * probs[cj] * __builtin_amdgcn_rsqf(TWO_PI_F * (vm + 2.0f * gamma));
        cv += (double)(c3 * c2);
    }

    double rec = 0.0, B = 0.0, cls = 0.0, lab = 0.0;
#pragma unroll
    for (int k = 0; k < 8; k++) {
        int idx = lane + 64 * k;
        rec += (double)recp[idx];
        B   += (double)Bp[idx];
        cls += (double)clsp[idx];
        lab += (double)labp[idx];
    }

    double AC = waveReduceD(av * invA + cv);
    rec = waveReduceD(rec);
    B   = waveReduceD(B);
    cls = waveReduceD(cls);
    lab = waveReduceD(lab);

    if (lane == 0) {
        double den = (lab == 0.0) ? 1.0 : lab;
        double cw = AC - B;
        double total = rec / (m * 64.0) + 8.0 + log(cw) + 2.0 * (cls / den);
        out[0] = (float)total;
    }
}

extern "C" void kernel_launch(void* const* d_in, const int* in_sizes, int n_in,
                              void* d_out, int out_size, void* d_ws, size_t ws_size,
                              hipStream_t stream) {
    (void)in_sizes; (void)n_in; (void)out_size; (void)ws_size;
    const float* batch = (const float*)d_in[0];
    const float* We1 = (const float*)d_in[1];
    const float* be1 = (const float*)d_in[2];
    const float* We2 = (const float*)d_in[3];
    const float* be2 = (const float*)d_in[4];
    const float* We3 = (const float*)d_in[5];
    const float* be3 = (const float*)d_in[6];
    const float* Wd1 = (const float*)d_in[7];
    const float* bd1 = (const float*)d_in[8];
    const float* Wd2 = (const float*)d_in[9];
    const float* bd2 = (const float*)d_in[10];
    const float* Wd3 = (const float*)d_in[11];
    const float* bd3 = (const float*)d_in[12];
    const float* means = (const float*)d_in[13];
    const float* vars = (const float*)d_in[14];
    const float* probs = (const float*)d_in[15];

    float* ws = (float*)d_ws;
    float2* zbuf = (float2*)ws;          // 4096 float2 = floats [0, 8192)
    float* Apart = ws + 8192;            // 2080
    float* recp  = ws + 12288;           // 512
    float* Bp    = ws + 12800;           // 512
    float* clsp  = ws + 13312;           // 512
    float* labp  = ws + 13824;           // 512
    int*   cnt   = (int*)(ws + 14336);   // 1 (zeroed by k_mlp each call)

    const float gamma = (float)pow(4.0 / (3.0 * (double)M_ROWS), 0.2);
    const float inv4g = 1.0f / (4.0f * gamma);

    k_mlp<<<NBLK_MLP, 64, 0, stream>>>(batch, We1, be1, We2, be2, We3, be3,
                                       Wd1, bd1, Wd2, bd2, Wd3, bd3,
                                       means, vars, probs,
                                       zbuf, recp, Bp, clsp, labp, cnt, gamma);
    k_pair<<<NPAIR, 64, 0, stream>>>(zbuf, Apart, recp, Bp, clsp, labp,
                                     means, vars, probs,
                                     (float*)d_out, cnt, inv4g, gamma);
}

// Round 6
// 117.218 us; speedup vs baseline: 1.3253x; 1.3253x over previous
//
#include <hip/hip_runtime.h>
#include <math.h>

#define M_ROWS 4096
#define IN_DIM 64
#define NCLS 10
#define ROW_STRIDE 74   // 64 tau + 10 labels
#define TWO_PI_F 6.283185307179586f
#define NPAIR 2080      // 64*65/2 upper-triangular tile pairs
#define NBLK_MLP 512    // 8 rows per block, 8 roles per row

// ---------------- phi (Bessel-I0-based) ----------------
__device__ __forceinline__ float phi_f_eval(float s) {
    float t = s * (1.0f / 7.5f);
    float t2 = t * t;
    float p = 0.0045813f;
    p = fmaf(p, t2, 0.0360768f);
    p = fmaf(p, t2, 0.2659732f);
    p = fmaf(p, t2, 1.2067492f);
    p = fmaf(p, t2, 3.0899424f);
    p = fmaf(p, t2, 3.5156229f);
    p = fmaf(p, t2, 1.0f);
    return __expf(-0.5f * s) * p;
}

__device__ __forceinline__ float phi_g_eval(float s) {
    float r = __builtin_amdgcn_rcpf(s);
    float u = 7.5f * r;
    float p = 0.00392377f;
    p = fmaf(p, u, -0.01647633f);
    p = fmaf(p, u, 0.02635537f);
    p = fmaf(p, u, -0.02057706f);
    p = fmaf(p, u, 0.0091628f);
    p = fmaf(p, u, -0.00157565f);
    p = fmaf(p, u, 0.00225319f);
    p = fmaf(p, u, 0.01328592f);
    p = fmaf(p, u, 0.39894228f);
    return __builtin_amdgcn_sqrtf(2.0f * r) * p;
}

#define PHI_F_75 0.21445709f   // phi_f(7.5)

__device__ __forceinline__ float phi_eval(float s) {
    float f = phi_f_eval(fminf(s, 7.5f));
    float g = phi_g_eval(fmaxf(s, 7.5f));
    return f - PHI_F_75 + g;
}

__device__ __forceinline__ float fast_tanh(float x) {
    float e = __expf(2.0f * x);
    float r = __builtin_amdgcn_rcpf(e + 1.0f);
    return fmaf(-2.0f, r, 1.0f);
}

__device__ __forceinline__ float waveReduce(float v) {
    v += __shfl_down(v, 32, 64);
    v += __shfl_down(v, 16, 64);
    v += __shfl_down(v, 8, 64);
    v += __shfl_down(v, 4, 64);
    v += __shfl_down(v, 2, 64);
    v += __shfl_down(v, 1, 64);
    return v;
}

__device__ __forceinline__ double waveReduceD(double v) {
    v += __shfl_down(v, 32, 64);
    v += __shfl_down(v, 16, 64);
    v += __shfl_down(v, 8, 64);
    v += __shfl_down(v, 4, 64);
    v += __shfl_down(v, 2, 64);
    v += __shfl_down(v, 1, 64);
    return v;
}

// register-select without dynamic indexing
__device__ __forceinline__ float sel4(float v0, float v1, float v2, float v3, int r) {
    float a = (r & 1) ? v1 : v0;
    float b = (r & 1) ? v3 : v2;
    return (r & 2) ? b : a;
}
__device__ __forceinline__ float sel8(float v0, float v1, float v2, float v3,
                                      float v4, float v5, float v6, float v7, int r) {
    float a = sel4(v0, v1, v2, v3, r);
    float b = sel4(v4, v5, v6, v7, r);
    return (r & 4) ? b : a;
}

// -------- LDS layout (floats), rows padded so 8 roles hit disjoint bank quads
#define P_W1   0        // 64 rows x stride 36
#define P_W2   2304     // 32 rows x stride 20
#define P_WD2  2944     // 16 rows x stride 36
#define P_WD3  3520     // 32 rows x stride 68
#define P_W3   5696     // 16x2
#define P_WD1  5728     // 2x16
#define P_B1   5760
#define P_B2   5792
#define P_B3   5808
#define P_BD1  5810
#define P_BD2  5826
#define P_BD3  5858
#define P_MU   5922
#define P_VAR  5942
#define P_PRB  5952
#define SMT    5962

// Kernel 1: MLP, 8 roles per row (row = tid&7, role = tid>>3), 512 blocks ->
// 2 waves/CU. Role r owns indices ≡ r (mod 8); butterfly shfl_xor(8/16/32)
// completes each dot-product in all lanes. (R4-verified, 116.9 µs total.)
__global__ __launch_bounds__(64, 1) void k_mlp(
    const float* __restrict__ batch,
    const float* __restrict__ We1, const float* __restrict__ be1,
    const float* __restrict__ We2, const float* __restrict__ be2,
    const float* __restrict__ We3, const float* __restrict__ be3,
    const float* __restrict__ Wd1, const float* __restrict__ bd1,
    const float* __restrict__ Wd2, const float* __restrict__ bd2,
    const float* __restrict__ Wd3, const float* __restrict__ bd3,
    const float* __restrict__ means, const float* __restrict__ vars,
    const float* __restrict__ probs,
    float2* __restrict__ zbuf,
    float* __restrict__ recp, float* __restrict__ Bp,
    float* __restrict__ clsp, float* __restrict__ labp,
    float gamma)
{
    __shared__ __align__(16) float sm[SMT];
    const int tid = threadIdx.x;

    for (int idx = tid; idx < 2048; idx += 64) { int i = idx >> 5, j = idx & 31; sm[P_W1  + i * 36 + j] = We1[idx]; }
    for (int idx = tid; idx < 512;  idx += 64) { int i = idx >> 4, j = idx & 15; sm[P_W2  + i * 20 + j] = We2[idx]; }
    for (int idx = tid; idx < 512;  idx += 64) { int i = idx >> 5, j = idx & 31; sm[P_WD2 + i * 36 + j] = Wd2[idx]; }
    for (int idx = tid; idx < 2048; idx += 64) { int i = idx >> 6, j = idx & 63; sm[P_WD3 + i * 68 + j] = Wd3[idx]; }
    if (tid < 32) sm[P_W3 + tid] = We3[tid];
    else          sm[P_WD1 + tid - 32] = Wd1[tid - 32];
    if (tid < 32) sm[P_B1 + tid] = be1[tid];
    if (tid < 16) sm[P_B2 + tid] = be2[tid];
    if (tid < 2)  sm[P_B3 + tid] = be3[tid];
    if (tid < 16) sm[P_BD1 + tid] = bd1[tid];
    if (tid < 32) sm[P_BD2 + tid] = bd2[tid];
    sm[P_BD3 + tid] = bd3[tid];
    if (tid < 20) sm[P_MU + tid] = means[tid];
    if (tid < 10) sm[P_VAR + tid] = vars[tid];
    if (tid < 10) sm[P_PRB + tid] = probs[tid];
    __syncthreads();

    const int rw = tid & 7;          // row within block
    const int r  = tid >> 3;         // role 0..7
    const int row = blockIdx.x * 8 + rw;
    const float* rp = batch + (size_t)row * ROW_STRIDE;

    float taus[8];
#pragma unroll
    for (int k = 0; k < 8; k++) taus[k] = rp[r + 8 * k];

    // ---- encoder L1: 64 -> 32 ----
    float a1[32];
#pragma unroll
    for (int j = 0; j < 32; j++) a1[j] = 0.0f;
#pragma unroll
    for (int k = 0; k < 8; k++) {
        const int i = r + 8 * k;
        const float4* wr = (const float4*)&sm[P_W1 + i * 36];
        const float ti = taus[k];
#pragma unroll
        for (int jj = 0; jj < 8; jj++) {
            float4 w = wr[jj];
            a1[4 * jj + 0] = fmaf(ti, w.x, a1[4 * jj + 0]);
            a1[4 * jj + 1] = fmaf(ti, w.y, a1[4 * jj + 1]);
            a1[4 * jj + 2] = fmaf(ti, w.z, a1[4 * jj + 2]);
            a1[4 * jj + 3] = fmaf(ti, w.w, a1[4 * jj + 3]);
        }
    }
#pragma unroll
    for (int j = 0; j < 32; j++) {
        a1[j] += __shfl_xor(a1[j], 8, 64);
        a1[j] += __shfl_xor(a1[j], 16, 64);
        a1[j] += __shfl_xor(a1[j], 32, 64);
    }
    float x1own[4];
#pragma unroll
    for (int k = 0; k < 4; k++)
        x1own[k] = fast_tanh(sel8(a1[8 * k], a1[8 * k + 1], a1[8 * k + 2], a1[8 * k + 3],
                                  a1[8 * k + 4], a1[8 * k + 5], a1[8 * k + 6], a1[8 * k + 7], r)
                             + sm[P_B1 + r + 8 * k]);

    // ---- encoder L2: 32 -> 16 ----
    float a2[16];
#pragma unroll
    for (int j = 0; j < 16; j++) a2[j] = 0.0f;
#pragma unroll
    for (int k = 0; k < 4; k++) {
        const int i = r + 8 * k;
        const float4* wr = (const float4*)&sm[P_W2 + i * 20];
        const float x = x1own[k];
#pragma unroll
        for (int jj = 0; jj < 4; jj++) {
            float4 w = wr[jj];
            a2[4 * jj + 0] = fmaf(x, w.x, a2[4 * jj + 0]);
            a2[4 * jj + 1] = fmaf(x, w.y, a2[4 * jj + 1]);
            a2[4 * jj + 2] = fmaf(x, w.z, a2[4 * jj + 2]);
            a2[4 * jj + 3] = fmaf(x, w.w, a2[4 * jj + 3]);
        }
    }
#pragma unroll
    for (int j = 0; j < 16; j++) {
        a2[j] += __shfl_xor(a2[j], 8, 64);
        a2[j] += __shfl_xor(a2[j], 16, 64);
        a2[j] += __shfl_xor(a2[j], 32, 64);
    }
    float x2own[2];
#pragma unroll
    for (int k = 0; k < 2; k++)
        x2own[k] = fast_tanh(sel8(a2[8 * k], a2[8 * k + 1], a2[8 * k + 2], a2[8 * k + 3],
                                  a2[8 * k + 4], a2[8 * k + 5], a2[8 * k + 6], a2[8 * k + 7], r)
                             + sm[P_B2 + r + 8 * k]);

    // ---- encoder L3: 16 -> 2 (z) ----
    float z0 = 0.0f, z1 = 0.0f;
#pragma unroll
    for (int k = 0; k < 2; k++) {
        const int i = r + 8 * k;
        z0 = fmaf(x2own[k], sm[P_W3 + 2 * i], z0);
        z1 = fmaf(x2own[k], sm[P_W3 + 2 * i + 1], z1);
    }
    z0 += __shfl_xor(z0, 8, 64); z0 += __shfl_xor(z0, 16, 64); z0 += __shfl_xor(z0, 32, 64);
    z1 += __shfl_xor(z1, 8, 64); z1 += __shfl_xor(z1, 16, 64); z1 += __shfl_xor(z1, 32, 64);
    z0 += sm[P_B3 + 0];
    z1 += sm[P_B3 + 1];
    if (r == 0) zbuf[row] = make_float2(z0, z1);

    // ---- decoder d1: 2 -> 16 ----
    float h1own[2];
#pragma unroll
    for (int k = 0; k < 2; k++) {
        const int j = r + 8 * k;
        float acc = sm[P_BD1 + j];
        acc = fmaf(z0, sm[P_WD1 + j], acc);
        acc = fmaf(z1, sm[P_WD1 + 16 + j], acc);
        h1own[k] = fast_tanh(acc);
    }

    // ---- decoder d2: 16 -> 32 ----
    float a3[32];
#pragma unroll
    for (int j = 0; j < 32; j++) a3[j] = 0.0f;
#pragma unroll
    for (int k = 0; k < 2; k++) {
        const int i = r + 8 * k;
        const float4* wr = (const float4*)&sm[P_WD2 + i * 36];
        const float x = h1own[k];
#pragma unroll
        for (int jj = 0; jj < 8; jj++) {
            float4 w = wr[jj];
            a3[4 * jj + 0] = fmaf(x, w.x, a3[4 * jj + 0]);
            a3[4 * jj + 1] = fmaf(x, w.y, a3[4 * jj + 1]);
            a3[4 * jj + 2] = fmaf(x, w.z, a3[4 * jj + 2]);
            a3[4 * jj + 3] = fmaf(x, w.w, a3[4 * jj + 3]);
        }
    }
#pragma unroll
    for (int j = 0; j < 32; j++) {
        a3[j] += __shfl_xor(a3[j], 8, 64);
        a3[j] += __shfl_xor(a3[j], 16, 64);
        a3[j] += __shfl_xor(a3[j], 32, 64);
    }
    float h2own[4];
#pragma unroll
    for (int k = 0; k < 4; k++)
        h2own[k] = fast_tanh(sel8(a3[8 * k], a3[8 * k + 1], a3[8 * k + 2], a3[8 * k + 3],
                                  a3[8 * k + 4], a3[8 * k + 5], a3[8 * k + 6], a3[8 * k + 7], r)
                             + sm[P_BD2 + r + 8 * k]);

    // ---- decoder d3: 32 -> 64 + rec ----
    float a4[64];
#pragma unroll
    for (int j = 0; j < 64; j++) a4[j] = 0.0f;
#pragma unroll
    for (int k = 0; k < 4; k++) {
        const int i = r + 8 * k;
        const float4* wr = (const float4*)&sm[P_WD3 + i * 68];
        const float x = h2own[k];
#pragma unroll
        for (int jj = 0; jj < 16; jj++) {
            float4 w = wr[jj];
            a4[4 * jj + 0] = fmaf(x, w.x, a4[4 * jj + 0]);
            a4[4 * jj + 1] = fmaf(x, w.y, a4[4 * jj + 1]);
            a4[4 * jj + 2] = fmaf(x, w.z, a4[4 * jj + 2]);
            a4[4 * jj + 3] = fmaf(x, w.w, a4[4 * jj + 3]);
        }
    }
#pragma unroll
    for (int j = 0; j < 64; j++) {
        a4[j] += __shfl_xor(a4[j], 8, 64);
        a4[j] += __shfl_xor(a4[j], 16, 64);
        a4[j] += __shfl_xor(a4[j], 32, 64);
    }
    float rec = 0.0f;
#pragma unroll
    for (int k = 0; k < 8; k++) {
        float dec = sel8(a4[8 * k], a4[8 * k + 1], a4[8 * k + 2], a4[8 * k + 3],
                         a4[8 * k + 4], a4[8 * k + 5], a4[8 * k + 6], a4[8 * k + 7], r)
                    + sm[P_BD3 + r + 8 * k];
        float e = dec - taus[k];
        rec = fmaf(e, e, rec);
    }

    // ---- B term + class CE: only role 0 (one lane per row) ----
    float Bacc = 0.0f, cls = 0.0f, suml = 0.0f;
    if (r == 0) {
        const float two_g = 2.0f * gamma;
        const float inv_m = 1.0f / (float)M_ROWS;
        float lg[NCLS];
        float mx = -3.0e38f;
#pragma unroll
        for (int c = 0; c < NCLS; c++) {
            float d0 = z0 - sm[P_MU + 2 * c];
            float d1 = z1 - sm[P_MU + 2 * c + 1];
            float sqc = fmaf(d0, d0, d1 * d1);
            float vc = sm[P_VAR + c];
            float lgc = __logf(sm[P_PRB + c]) - __logf(TWO_PI_F * vc)
                        - sqc * 0.5f * __builtin_amdgcn_rcpf(vc);
            lg[c] = lgc;
            mx = fmaxf(mx, lgc);

            float den = vc + two_g;
            float sB = sqc * 0.5f * __builtin_amdgcn_rcpf(den);
            float coef = 2.0f * inv_m * sm[P_PRB + c] * __builtin_amdgcn_rsqf(TWO_PI_F * den);
            Bacc = fmaf(coef, phi_eval(sB), Bacc);
        }
        float esum = 0.0f;
#pragma unroll
        for (int c = 0; c < NCLS; c++) esum += __expf(lg[c] - mx);
        float lse = __logf(esum) + mx;

        float ce = 0.0f;
#pragma unroll
        for (int c = 0; c < NCLS; c++) {
            float lb = rp[IN_DIM + c];
            suml += lb;
            ce = fmaf(lb, lse - lg[c], ce);
        }
        cls = (suml == 1.0f) ? ce : 0.0f;
    }

    float r0 = waveReduce(rec);
    float r1 = waveReduce(Bacc);
    float r2 = waveReduce(cls);
    float r3 = waveReduce(suml);
    if (tid == 0) {
        recp[blockIdx.x] = r0;
        Bp[blockIdx.x]   = r1;
        clsp[blockIdx.x] = r2;
        labp[blockIdx.x] = r3;
    }
}

// Kernel 2: pairwise A term. Triangular grid; diagonal tiles counted once,
// off-diagonal weighted x2. NO fence/atomic — R5 showed per-block device-scope
// __threadfence + contended atomicAdd costs ~38 µs on 8 non-coherent XCDs.
__global__ __launch_bounds__(64, 4) void k_pair(
    const float2* __restrict__ z, float* __restrict__ Apart, float inv4g)
{
    const int p = blockIdx.x;
    int tj = (int)((__builtin_amdgcn_sqrtf(8.0f * (float)p + 1.0f) - 1.0f) * 0.5f);
    while ((tj + 1) * (tj + 2) / 2 <= p) tj++;
    while (tj * (tj + 1) / 2 > p) tj--;
    const int ti = p - tj * (tj + 1) / 2;

    const int lane = threadIdx.x;
    __shared__ float2 zjs[64];
    float2 zi = z[ti * 64 + lane];
    zjs[lane] = z[tj * 64 + lane];
    __syncthreads();

    float acc0 = 0.0f, acc1 = 0.0f;
#pragma unroll 8
    for (int jj = 0; jj < 64; jj += 2) {
        float2 a = zjs[jj], b = zjs[jj + 1];
        float dx0 = zi.x - a.x, dy0 = zi.y - a.y;
        float dx1 = zi.x - b.x, dy1 = zi.y - b.y;
        acc0 += phi_eval(fmaf(dx0, dx0, dy0 * dy0) * inv4g);
        acc1 += phi_eval(fmaf(dx1, dx1, dy1 * dy1) * inv4g);
    }
    float tot = waveReduce(acc0 + acc1);
    if (lane == 0) Apart[p] = (ti == tj) ? tot : 2.0f * tot;
}

// Kernel 3: finalize (R4-verified). Partial arrays are 512 entries each.
__global__ __launch_bounds__(256) void k_fin(
    const float* __restrict__ means, const float* __restrict__ vars,
    const float* __restrict__ probs,
    const float* __restrict__ Apart,
    const float* __restrict__ recp, const float* __restrict__ Bp,
    const float* __restrict__ clsp, const float* __restrict__ labp,
    float* __restrict__ out, float gamma)
{
    __shared__ double wsum[8];
    const int t = threadIdx.x;
    const int w = t >> 6;
    const int l = t & 63;

    const double m = (double)M_ROWS;
    const double gam = (double)gamma;
    const double invA = 1.0 / (m * m * sqrt(2.0 * M_PI * 2.0 * gam));

    double av = 0.0;
#pragma unroll
    for (int k = 0; k < 9; k++) {
        int idx = t + 256 * k;
        if (idx < NPAIR) av += (double)Apart[idx];
    }

    double cv = 0.0;
    if (t < 100) {
        int ci = t / 10, cj = t - 10 * (t / 10);
        float vm = vars[ci] + vars[cj];
        float d0 = means[2 * ci] - means[2 * cj];
        float d1 = means[2 * ci + 1] - means[2 * cj + 1];
        float c1 = fmaf(d0, d0, d1 * d1);
        float s = c1 / (2.0f * vm + 4.0f * gamma);
        float c2 = phi_eval(s);
        float c3 = probs[ci] * probs[cj] * __builtin_amdgcn_rsqf(TWO_PI_F * (vm + 2.0f * gamma));
        cv = (double)(c3 * c2);
    }

    double acw = waveReduceD(av * invA + cv);

    const float* arr = (w == 0) ? recp : (w == 1) ? Bp : (w == 2) ? clsp : labp;
    double pv = 0.0;
#pragma unroll
    for (int k = 0; k < 8; k++) pv += (double)arr[l + 64 * k];
    double pw = waveReduceD(pv);

    if (l == 0) { wsum[w] = acw; wsum[4 + w] = pw; }
    __syncthreads();

    if (t == 0) {
        double AC = wsum[0] + wsum[1] + wsum[2] + wsum[3];
        double rec = wsum[4], B = wsum[5], cls = wsum[6], lab = wsum[7];
        double den = (lab == 0.0) ? 1.0 : lab;
        double cw = AC - B;
        double total = rec / (m * 64.0) + 8.0 + log(cw) + 2.0 * (cls / den);
        out[0] = (float)total;
    }
}

extern "C" void kernel_launch(void* const* d_in, const int* in_sizes, int n_in,
                              void* d_out, int out_size, void* d_ws, size_t ws_size,
                              hipStream_t stream) {
    (void)in_sizes; (void)n_in; (void)out_size; (void)ws_size;
    const float* batch = (const float*)d_in[0];
    const float* We1 = (const float*)d_in[1];
    const float* be1 = (const float*)d_in[2];
    const float* We2 = (const float*)d_in[3];
    const float* be2 = (const float*)d_in[4];
    const float* We3 = (const float*)d_in[5];
    const float* be3 = (const float*)d_in[6];
    const float* Wd1 = (const float*)d_in[7];
    const float* bd1 = (const float*)d_in[8];
    const float* Wd2 = (const float*)d_in[9];
    const float* bd2 = (const float*)d_in[10];
    const float* Wd3 = (const float*)d_in[11];
    const float* bd3 = (const float*)d_in[12];
    const float* means = (const float*)d_in[13];
    const float* vars = (const float*)d_in[14];
    const float* probs = (const float*)d_in[15];

    float* ws = (float*)d_ws;
    float2* zbuf = (float2*)ws;          // 4096 float2 = floats [0, 8192)
    float* Apart = ws + 8192;            // 2080
    float* recp  = ws + 12288;           // 512
    float* Bp    = ws + 12800;           // 512
    float* clsp  = ws + 13312;           // 512
    float* labp  = ws + 13824;           // 512

    const float gamma = (float)pow(4.0 / (3.0 * (double)M_ROWS), 0.2);
    const float inv4g = 1.0f / (4.0f * gamma);

    k_mlp<<<NBLK_MLP, 64, 0, stream>>>(batch, We1, be1, We2, be2, We3, be3,
                                       Wd1, bd1, Wd2, bd2, Wd3, bd3,
                                       means, vars, probs,
                                       zbuf, recp, Bp, clsp, labp, gamma);
    k_pair<<<NPAIR, 64, 0, stream>>>(zbuf, Apart, inv4g);
    k_fin<<<1, 256, 0, stream>>>(means, vars, probs, Apart, recp, Bp, clsp, labp,
                                 (float*)d_out, gamma);
}